// Round 1
// baseline (77.491 us; speedup 1.0000x reference)
//
#include <hip/hip_runtime.h>

// C[y][v] = cos((2y+1)*v*pi/16), row-major. Shared by a compile-time-literal
// copy (row pass, constant indices -> folds to literals) and a __constant__
// copy (column pass, runtime lane index u -> 8 cached loads).
#define DCT_ROWS \
  {1.0f,  0.98078528f,  0.92387953f,  0.83146961f,  0.70710678f,  0.55557023f,  0.38268343f,  0.19509032f}, \
  {1.0f,  0.83146961f,  0.38268343f, -0.19509032f, -0.70710678f, -0.98078528f, -0.92387953f, -0.55557023f}, \
  {1.0f,  0.55557023f, -0.38268343f, -0.98078528f, -0.70710678f,  0.19509032f,  0.92387953f,  0.83146961f}, \
  {1.0f,  0.19509032f, -0.92387953f, -0.55557023f,  0.70710678f,  0.83146961f, -0.38268343f, -0.98078528f}, \
  {1.0f, -0.19509032f, -0.92387953f,  0.55557023f,  0.70710678f, -0.83146961f, -0.38268343f,  0.98078528f}, \
  {1.0f, -0.55557023f, -0.38268343f,  0.98078528f, -0.70710678f, -0.19509032f,  0.92387953f, -0.83146961f}, \
  {1.0f, -0.83146961f,  0.38268343f,  0.19509032f, -0.70710678f,  0.98078528f, -0.92387953f,  0.55557023f}, \
  {1.0f, -0.98078528f,  0.92387953f, -0.83146961f,  0.70710678f, -0.55557023f,  0.38268343f, -0.19509032f}

__constant__ float gC[8][8] = { DCT_ROWS };

// 8 lanes per 8x8 block; lane t = row t for the load/row-pass, then acts as
// output row u for the column pass. All loads/stores are two float4 per lane
// at lane-contiguous addresses (32 B/lane) -> fully coalesced streaming.
__global__ __launch_bounds__(256) void dct8x8_kernel(const float* __restrict__ in,
                                                     float* __restrict__ out,
                                                     int nthreads) {
    constexpr float Ch[8][8] = { DCT_ROWS };

    const int tid = blockIdx.x * 256 + threadIdx.x;
    if (tid >= nthreads) return;          // exact division in practice; full waves
    const int u = threadIdx.x & 7;        // lane-in-group = row / output row

    // ---- load one 8-float row (32 B), subtract 128 ----
    const float4* p = reinterpret_cast<const float4*>(in) + (size_t)tid * 2;
    float4 v0 = p[0];
    float4 v1 = p[1];
    float a[8] = { v0.x - 128.0f, v0.y - 128.0f, v0.z - 128.0f, v0.w - 128.0f,
                   v1.x - 128.0f, v1.y - 128.0f, v1.z - 128.0f, v1.w - 128.0f };

    // ---- row pass: r[v] = sum_y a[y] * C[y][v]  (all-literal coefficients) ----
    float r[8];
#pragma unroll
    for (int v = 0; v < 8; ++v) {
        float s = 0.0f;
#pragma unroll
        for (int y = 0; y < 8; ++y) s = fmaf(a[y], Ch[y][v], s);
        r[v] = s;
    }

    // ---- per-lane column of C: Ccol[x] = C[x][u]  (8 L1-cached loads) ----
    float Ccol[8];
#pragma unroll
    for (int x = 0; x < 8; ++x) Ccol[x] = gC[x][u];

    // ---- column pass: o[v] = sum_x C[x][u] * r_lane_x[v]  via 8-wide shuffles ----
    float o[8] = {0.0f, 0.0f, 0.0f, 0.0f, 0.0f, 0.0f, 0.0f, 0.0f};
#pragma unroll
    for (int x = 0; x < 8; ++x) {
#pragma unroll
        for (int v = 0; v < 8; ++v) {
            float rx = __shfl(r[v], x, 8);       // broadcast lane x within 8-group
            o[v] = fmaf(Ccol[x], rx, o[v]);
        }
    }

    // ---- scale: scale[u][v] = (0.5*alpha_u)*(0.5*alpha_v) ----
    const float su = (u == 0) ? 0.35355339059f : 0.5f;
#pragma unroll
    for (int v = 0; v < 8; ++v) {
        const float sv = (v == 0) ? 0.35355339059f : 0.5f;  // compile-time select
        o[v] *= su * sv;
    }

    // ---- store row u of the block (same addresses as the load) ----
    float4* q = reinterpret_cast<float4*>(out) + (size_t)tid * 2;
    q[0] = make_float4(o[0], o[1], o[2], o[3]);
    q[1] = make_float4(o[4], o[5], o[6], o[7]);
}

extern "C" void kernel_launch(void* const* d_in, const int* in_sizes, int n_in,
                              void* d_out, int out_size, void* d_ws, size_t ws_size,
                              hipStream_t stream) {
    const float* in = (const float*)d_in[0];
    float* out = (float*)d_out;
    const int n = in_sizes[0];          // 64*3*4096*64 = 50,331,648 floats
    const int nthreads = n / 8;         // one lane per 8-float row
    const int grid = (nthreads + 255) / 256;
    hipLaunchKernelGGL(dct8x8_kernel, dim3(grid), dim3(256), 0, stream,
                       in, out, nthreads);
}